// Round 1
// baseline (3290.989 us; speedup 1.0000x reference)
//
#include <hip/hip_runtime.h>
#include <math.h>

#define B_ 4
#define N_ 4096
#define DIM_ 512
#define H_ 8
#define DH_ 64
#define M_ 256
#define BH_ (B_*H_)

// ---------------- LayerNorm ----------------
__global__ void ln_kernel(const float* __restrict__ x, const float* __restrict__ w,
                          const float* __restrict__ b, float* __restrict__ xn) {
  int row = blockIdx.x;              // 16384 rows
  const float* xr = x + (size_t)row * DIM_;
  int t = threadIdx.x;               // 256
  float v0 = xr[t], v1 = xr[t + 256];
  float s = v0 + v1, ss = v0*v0 + v1*v1;
  for (int o = 32; o > 0; o >>= 1) { s += __shfl_down(s, o); ss += __shfl_down(ss, o); }
  __shared__ float ls[4], lss[4];
  int wid = t >> 6, lane = t & 63;
  if (lane == 0) { ls[wid] = s; lss[wid] = ss; }
  __syncthreads();
  float tot  = ls[0]+ls[1]+ls[2]+ls[3];
  float tot2 = lss[0]+lss[1]+lss[2]+lss[3];
  float mean = tot * (1.f/DIM_);
  float var  = tot2 * (1.f/DIM_) - mean*mean;
  float inv = rsqrtf(var + 1e-5f);
  float* xo = xn + (size_t)row * DIM_;
  xo[t]       = (v0-mean)*inv*w[t]       + b[t];
  xo[t+256]   = (v1-mean)*inv*w[t+256]   + b[t+256];
}

// ---------------- QKV GEMM: xn[16384,512] @ w_qkv[512,1536], scatter to heads ----------------
__global__ void qkv_gemm(const float* __restrict__ A, const float* __restrict__ W,
                         float* __restrict__ q, float* __restrict__ k, float* __restrict__ v) {
  __shared__ float As[16][65];
  __shared__ float Bs[16][64];
  int t = threadIdx.x, tx = t & 15, ty = t >> 4;
  int row0 = blockIdx.y * 64, col0 = blockIdx.x * 64;
  float acc[4][4] = {};
  for (int k0 = 0; k0 < 512; k0 += 16) {
    for (int i = t; i < 1024; i += 256) {
      int r = i >> 4, c = i & 15;
      As[c][r] = A[(size_t)(row0 + r) * 512 + k0 + c];
      int rb = i >> 6, cb = i & 63;
      Bs[rb][cb] = W[(size_t)(k0 + rb) * 1536 + col0 + cb];
    }
    __syncthreads();
    for (int kk = 0; kk < 16; kk++) {
      float a[4], b[4];
      #pragma unroll
      for (int i = 0; i < 4; i++) a[i] = As[kk][ty*4+i];
      #pragma unroll
      for (int j = 0; j < 4; j++) b[j] = Bs[kk][tx*4+j];
      #pragma unroll
      for (int i = 0; i < 4; i++)
        #pragma unroll
        for (int j = 0; j < 4; j++) acc[i][j] += a[i]*b[j];
    }
    __syncthreads();
  }
  for (int i = 0; i < 4; i++) {
    int row = row0 + ty*4 + i;
    int b_ = row >> 12, n = row & 4095;
    for (int j = 0; j < 4; j++) {
      int col = col0 + tx*4 + j;
      int part = col >> 9, rem = col & 511;
      int h = rem >> 6, d = rem & 63;
      size_t dst = (((size_t)(b_*H_ + h)) * N_ + n) * DH_ + d;
      float val = acc[i][j];
      if (part == 0)      q[dst] = val * 0.125f;   // DH^-0.5
      else if (part == 1) k[dst] = val;
      else                v[dst] = val;
    }
  }
}

// ---------------- landmarks: mean over blocks of 16 tokens ----------------
__global__ void landmark_kernel(const float* __restrict__ q, const float* __restrict__ k,
                                float* __restrict__ ql, float* __restrict__ kl) {
  int idx = blockIdx.x;              // bh*256 + m  (8192)
  int d = threadIdx.x;               // 64
  size_t base = ((size_t)idx * 16) * 64 + d;   // idx*16 == bh*4096 + m*16
  float sq = 0.f, sk = 0.f;
  #pragma unroll
  for (int j = 0; j < 16; j++) { sq += q[base + (size_t)j*64]; sk += k[base + (size_t)j*64]; }
  ql[(size_t)idx*64 + d] = sq * (1.f/16.f);
  kl[(size_t)idx*64 + d] = sk * (1.f/16.f);
}

// ---------------- sim2 = ql @ kl^T row, softmax ----------------
__global__ void sim2_softmax(const float* __restrict__ ql, const float* __restrict__ kl,
                             float* __restrict__ a2) {
  int bh = blockIdx.x >> 8;
  int row = blockIdx.x & 255;
  int t = threadIdx.x;               // 256
  __shared__ float qr[64];
  __shared__ float red[256];
  if (t < 64) qr[t] = ql[((size_t)bh*256 + row)*64 + t];
  __syncthreads();
  const float* kr = kl + ((size_t)bh*256 + t)*64;
  float s = 0.f;
  for (int d = 0; d < 64; d++) s += qr[d]*kr[d];
  red[t] = s; __syncthreads();
  for (int o = 128; o > 0; o >>= 1) { if (t < o) red[t] = fmaxf(red[t], red[t+o]); __syncthreads(); }
  float mx = red[0]; __syncthreads();
  float p = expf(s - mx);
  red[t] = p; __syncthreads();
  for (int o = 128; o > 0; o >>= 1) { if (t < o) red[t] += red[t+o]; __syncthreads(); }
  float inv = 1.f / red[0];
  a2[((size_t)bh*256 + row)*256 + t] = p * inv;
}

// ---------------- global max of row-sums and col-sums of a2 ----------------
__global__ void absmax_kernel(const float* __restrict__ a2, unsigned* __restrict__ scal) {
  int bh = blockIdx.x; int t = threadIdx.x;  // 32 blocks x 256
  float rs = 0.f, cs = 0.f;
  const float* rp = a2 + ((size_t)bh*256 + t)*256;
  for (int j = 0; j < 256; j++) rs += rp[j];
  const float* cp = a2 + (size_t)bh*65536 + t;
  for (int i = 0; i < 256; i++) cs += cp[(size_t)i*256];
  __shared__ float r1[256], r2[256];
  r1[t] = rs; r2[t] = cs; __syncthreads();
  for (int o = 128; o > 0; o >>= 1) {
    if (t < o) { r1[t]=fmaxf(r1[t],r1[t+o]); r2[t]=fmaxf(r2[t],r2[t+o]); }
    __syncthreads();
  }
  if (t == 0) {
    atomicMax(scal + 0, __float_as_uint(r1[0]));   // ref "col" = abs.sum(-1) = row sums
    atomicMax(scal + 1, __float_as_uint(r2[0]));   // ref "row" = abs.sum(-2) = col sums
  }
}

// ---------------- z0 = a2^T / (cmax*rmax) ----------------
__global__ void z0_kernel(const float* __restrict__ a2, const unsigned* __restrict__ scal,
                          float* __restrict__ z) {
  size_t idx = (size_t)blockIdx.x*256 + threadIdx.x;   // 32*65536 total
  float inv = 1.f / (__uint_as_float(scal[0]) * __uint_as_float(scal[1]));
  size_t bh = idx >> 16; int rem = (int)(idx & 65535); int i = rem >> 8, j = rem & 255;
  z[idx] = a2[(bh<<16) + ((size_t)j<<8) + i] * inv;
}

// ---------------- e = diag*I - in ----------------
__global__ void ew_diag_kernel(const float* __restrict__ in, float* __restrict__ out, float diag) {
  size_t idx = (size_t)blockIdx.x*256 + threadIdx.x;
  int rem = (int)(idx & 65535); int i = rem >> 8, j = rem & 255;
  out[idx] = ((i==j) ? diag : 0.f) - in[idx];
}

// ---------------- batched GEMM: C = alpha*(A@B) + diag*I ----------------
__global__ void bmm_kernel(const float* __restrict__ A, const float* __restrict__ B,
                           float* __restrict__ C, int M, int N, int K, float alpha, float diag) {
  int batch = blockIdx.z;
  const float* Ab = A + (size_t)batch*M*K;
  const float* Bb = B + (size_t)batch*K*N;
  float* Cb = C + (size_t)batch*M*N;
  __shared__ float As[16][65];
  __shared__ float Bs[16][64];
  int t = threadIdx.x, tx = t & 15, ty = t >> 4;
  int row0 = blockIdx.y*64, col0 = blockIdx.x*64;
  float acc[4][4] = {};
  for (int k0 = 0; k0 < K; k0 += 16) {
    for (int i = t; i < 1024; i += 256) {
      int r = i >> 4, c = i & 15;
      As[c][r] = Ab[(size_t)(row0+r)*K + k0 + c];
      int rb = i >> 6, cb = i & 63;
      if (cb < N) Bs[rb][cb] = Bb[(size_t)(k0+rb)*N + col0 + cb];
    }
    __syncthreads();
    for (int kk = 0; kk < 16; kk++) {
      float a[4], b[4];
      #pragma unroll
      for (int i = 0; i < 4; i++) a[i] = As[kk][ty*4+i];
      #pragma unroll
      for (int j = 0; j < 4; j++) b[j] = Bs[kk][tx*4+j];
      #pragma unroll
      for (int i = 0; i < 4; i++)
        #pragma unroll
        for (int j = 0; j < 4; j++) acc[i][j] += a[i]*b[j];
    }
    __syncthreads();
  }
  for (int i = 0; i < 4; i++) {
    int row = row0 + ty*4 + i;
    for (int j = 0; j < 4; j++) {
      int col = col0 + tx*4 + j;
      if (col < N)
        Cb[(size_t)row*N + col] = alpha*acc[i][j] + ((row==col) ? diag : 0.f);
    }
  }
}

// ---------------- flash-style: O = softmax(Q K^T) V   (D=64) ----------------
__global__ void flash_kernel(const float* __restrict__ Q, const float* __restrict__ K,
                             const float* __restrict__ V, float* __restrict__ O,
                             int NQ, int NK) {
  int bh = blockIdx.y;
  int q0 = blockIdx.x * 32;
  __shared__ float qs[32][65];
  __shared__ float kt[64][65];
  __shared__ float vt[64][65];
  __shared__ float sc[32][65];
  __shared__ float mrow[32], lrow[32], scl[32];
  int t = threadIdx.x;   // 256
  const float* Qb = Q + (size_t)bh*NQ*64;
  const float* Kb = K + (size_t)bh*NK*64;
  const float* Vb = V + (size_t)bh*NK*64;
  for (int i = t; i < 2048; i += 256) qs[i>>6][i&63] = Qb[(size_t)(q0 + (i>>6))*64 + (i&63)];
  if (t < 32) { mrow[t] = -1e30f; lrow[t] = 0.f; }
  float acc[8] = {};
  int d = t & 63, qb = t >> 6;
  int qq0 = (t >> 4) << 1, kk0 = (t & 15) << 2;
  __syncthreads();
  for (int k0 = 0; k0 < NK; k0 += 64) {
    for (int i = t; i < 4096; i += 256) {
      int r = i >> 6, c = i & 63;
      kt[r][c] = Kb[(size_t)(k0+r)*64 + c];
      vt[r][c] = Vb[(size_t)(k0+r)*64 + c];
    }
    __syncthreads();
    // scores: 2x4 micro-tile per thread
    float s00=0,s01=0,s02=0,s03=0,s10=0,s11=0,s12=0,s13=0;
    for (int dd = 0; dd < 64; dd++) {
      float a0 = qs[qq0][dd], a1 = qs[qq0+1][dd];
      float b0 = kt[kk0][dd], b1 = kt[kk0+1][dd], b2 = kt[kk0+2][dd], b3 = kt[kk0+3][dd];
      s00 += a0*b0; s01 += a0*b1; s02 += a0*b2; s03 += a0*b3;
      s10 += a1*b0; s11 += a1*b1; s12 += a1*b2; s13 += a1*b3;
    }
    sc[qq0][kk0]=s00; sc[qq0][kk0+1]=s01; sc[qq0][kk0+2]=s02; sc[qq0][kk0+3]=s03;
    sc[qq0+1][kk0]=s10; sc[qq0+1][kk0+1]=s11; sc[qq0+1][kk0+2]=s12; sc[qq0+1][kk0+3]=s13;
    __syncthreads();
    // online softmax row pass: 8 lanes per row
    {
      int row = t >> 3, l8 = t & 7;
      float mx = -1e30f;
      for (int j = l8; j < 64; j += 8) mx = fmaxf(mx, sc[row][j]);
      for (int o = 1; o < 8; o <<= 1) mx = fmaxf(mx, __shfl_xor(mx, o));
      float mold = mrow[row];
      float mn = fmaxf(mold, mx);
      float sum = 0.f;
      for (int j = l8; j < 64; j += 8) { float p = expf(sc[row][j] - mn); sc[row][j] = p; sum += p; }
      for (int o = 1; o < 8; o <<= 1) sum += __shfl_xor(sum, o);
      if (l8 == 0) {
        float sf = expf(mold - mn);
        scl[row] = sf;
        lrow[row] = lrow[row]*sf + sum;
        mrow[row] = mn;
      }
    }
    __syncthreads();
    // PV accumulate
    {
      float av[8];
      #pragma unroll
      for (int j = 0; j < 8; j++) av[j] = acc[j] * scl[qb + (j<<2)];
      for (int kk = 0; kk < 64; kk++) {
        float vv = vt[kk][d];
        #pragma unroll
        for (int j = 0; j < 8; j++) av[j] += sc[qb + (j<<2)][kk] * vv;
      }
      #pragma unroll
      for (int j = 0; j < 8; j++) acc[j] = av[j];
    }
    __syncthreads();
  }
  #pragma unroll
  for (int j = 0; j < 8; j++) {
    int row = qb + (j << 2);
    O[((size_t)bh*NQ + q0 + row)*64 + d] = acc[j] / lrow[row];
  }
}

// ---------------- residual depthwise conv along N, add into outh ----------------
__global__ void conv_kernel(const float* __restrict__ v, const float* __restrict__ rw,
                            float* __restrict__ outh) {
  size_t i = (size_t)blockIdx.x*256 + threadIdx.x;  // 8,388,608
  int d = (int)(i & 63);
  size_t r = i >> 6;
  int n = (int)(r & 4095);
  int bh = (int)(r >> 12);
  int h = bh & 7;
  const float* vb = v + ((size_t)bh*4096)*64 + d;
  float s = 0.f;
  #pragma unroll
  for (int j = 0; j < 33; j++) {
    int nn = n + j - 16;
    if (nn >= 0 && nn < 4096) s += vb[(size_t)nn*64] * rw[h*33 + j];
  }
  outh[i] += s;
}

// ---------------- out GEMM: gather heads, @ w_out, + b_out + x ----------------
__global__ void out_gemm(const float* __restrict__ outh, const float* __restrict__ Wo,
                         const float* __restrict__ bo, const float* __restrict__ x,
                         float* __restrict__ out) {
  __shared__ float As[16][65];
  __shared__ float Bs[16][64];
  int t = threadIdx.x, tx = t & 15, ty = t >> 4;
  int row0 = blockIdx.y*64, col0 = blockIdx.x*64;
  float acc[4][4] = {};
  for (int k0 = 0; k0 < 512; k0 += 16) {
    for (int i = t; i < 1024; i += 256) {
      int r = i >> 4, c = i & 15;
      int row = row0 + r, kk = k0 + c;
      int b_ = row >> 12, n = row & 4095, h = kk >> 6, d = kk & 63;
      As[c][r] = outh[(((size_t)(b_*8+h))*4096 + n)*64 + d];
      int rb = i >> 6, cb = i & 63;
      Bs[rb][cb] = Wo[(size_t)(k0+rb)*512 + col0 + cb];
    }
    __syncthreads();
    for (int kk = 0; kk < 16; kk++) {
      float a[4], b[4];
      #pragma unroll
      for (int i = 0; i < 4; i++) a[i] = As[kk][ty*4+i];
      #pragma unroll
      for (int j = 0; j < 4; j++) b[j] = Bs[kk][tx*4+j];
      #pragma unroll
      for (int i = 0; i < 4; i++)
        #pragma unroll
        for (int j = 0; j < 4; j++) acc[i][j] += a[i]*b[j];
    }
    __syncthreads();
  }
  for (int i = 0; i < 4; i++) {
    int row = row0 + ty*4 + i;
    for (int j = 0; j < 4; j++) {
      int col = col0 + tx*4 + j;
      out[(size_t)row*512 + col] = x[(size_t)row*512 + col] + acc[i][j] + bo[col];
    }
  }
}

extern "C" void kernel_launch(void* const* d_in, const int* in_sizes, int n_in,
                              void* d_out, int out_size, void* d_ws, size_t ws_size,
                              hipStream_t stream) {
  const float* x      = (const float*)d_in[0];
  const float* norm_w = (const float*)d_in[1];
  const float* norm_b = (const float*)d_in[2];
  const float* w_qkv  = (const float*)d_in[3];
  const float* w_out  = (const float*)d_in[4];
  const float* b_out  = (const float*)d_in[5];
  const float* res_w  = (const float*)d_in[6];
  float* out = (float*)d_out;
  float* ws = (float*)d_ws;

  size_t off = 0;
  float* xn  = ws + off; off += 8388608;   // reused as outh after qkv
  float* q   = ws + off; off += 8388608;
  float* k   = ws + off; off += 8388608;
  float* v   = ws + off; off += 8388608;
  float* ql  = ws + off; off += 524288;
  float* kl  = ws + off; off += 524288;
  float* a2  = ws + off; off += 2097152;
  float* zA  = ws + off; off += 2097152;
  float* zB  = ws + off; off += 2097152;
  float* xz  = ws + off; off += 2097152;
  float* e1  = ws + off; off += 2097152;
  float* e2  = ws + off; off += 2097152;
  float* e3  = ws + off; off += 2097152;
  float* a3v = ws + off; off += 524288;
  float* w2  = ws + off; off += 524288;
  unsigned* scal = (unsigned*)(ws + off); off += 2;

  ln_kernel<<<16384, 256, 0, stream>>>(x, norm_w, norm_b, xn);
  qkv_gemm<<<dim3(24, 256), 256, 0, stream>>>(xn, w_qkv, q, k, v);
  landmark_kernel<<<8192, 64, 0, stream>>>(q, k, ql, kl);
  sim2_softmax<<<8192, 256, 0, stream>>>(ql, kl, a2);
  hipMemsetAsync(scal, 0, 8, stream);
  absmax_kernel<<<32, 256, 0, stream>>>(a2, scal);
  z0_kernel<<<8192, 256, 0, stream>>>(a2, scal, zA);

  float* zc = zA; float* zn = zB;
  for (int it = 0; it < 6; it++) {
    bmm_kernel<<<dim3(4,4,32), 256, 0, stream>>>(a2, zc, xz, 256,256,256, 1.f, 0.f);
    ew_diag_kernel<<<8192, 256, 0, stream>>>(xz, e1, 7.f);
    bmm_kernel<<<dim3(4,4,32), 256, 0, stream>>>(xz, e1, e2, 256,256,256, -1.f, 15.f);
    bmm_kernel<<<dim3(4,4,32), 256, 0, stream>>>(xz, e2, e3, 256,256,256, -1.f, 13.f);
    bmm_kernel<<<dim3(4,4,32), 256, 0, stream>>>(zc, e3, zn, 256,256,256, 0.25f, 0.f);
    float* tmp = zc; zc = zn; zn = tmp;
  }

  // a3v = softmax(ql @ k^T) @ v   -> [bh,256,64]
  flash_kernel<<<dim3(8, 32), 256, 0, stream>>>(ql, k, v, a3v, 256, 4096);
  // w2 = a2_inv @ a3v            -> [bh,256,64]
  bmm_kernel<<<dim3(1,4,32), 256, 0, stream>>>(zc, a3v, w2, 256, 64, 256, 1.f, 0.f);
  // outh = softmax(q @ kl^T) @ w2 -> [bh,4096,64]  (into xn buffer)
  flash_kernel<<<dim3(128, 32), 256, 0, stream>>>(q, kl, w2, xn, 4096, 256);
  // outh += depthwise conv of v
  conv_kernel<<<32768, 256, 0, stream>>>(v, res_w, xn);
  // out = x + outh @ w_out + b_out
  out_gemm<<<dim3(8, 256), 256, 0, stream>>>(xn, w_out, b_out, x, out);
}

// Round 2
// 629.331 us; speedup vs baseline: 5.2293x; 5.2293x over previous
//
#include <hip/hip_runtime.h>
#include <math.h>

typedef unsigned short u16;
typedef short s16x8 __attribute__((ext_vector_type(8)));
typedef float f32x4 __attribute__((ext_vector_type(4)));

#define MFMA16(a, b, c) __builtin_amdgcn_mfma_f32_16x16x32_bf16((a), (b), (c), 0, 0, 0)

__device__ __forceinline__ u16 f2b(float f) {
  unsigned u = __float_as_uint(f);
  unsigned r = (u + 0x7fff + ((u >> 16) & 1)) >> 16;
  return (u16)r;
}
__device__ __forceinline__ float b2f(u16 h) { return __uint_as_float(((unsigned)h) << 16); }

// ---------------- LayerNorm -> bf16 ----------------
__global__ __launch_bounds__(256) void ln_kernel(const float* __restrict__ x, const float* __restrict__ w,
                          const float* __restrict__ b, u16* __restrict__ xn) {
  int row = blockIdx.x;
  const float* xr = x + (size_t)row * 512;
  int t = threadIdx.x;
  float v0 = xr[t], v1 = xr[t + 256];
  float s = v0 + v1, ss = v0*v0 + v1*v1;
  for (int o = 32; o > 0; o >>= 1) { s += __shfl_down(s, o); ss += __shfl_down(ss, o); }
  __shared__ float ls[4], lss[4];
  int wid = t >> 6, lane = t & 63;
  if (lane == 0) { ls[wid] = s; lss[wid] = ss; }
  __syncthreads();
  float tot  = ls[0]+ls[1]+ls[2]+ls[3];
  float tot2 = lss[0]+lss[1]+lss[2]+lss[3];
  float mean = tot * (1.f/512);
  float var  = tot2 * (1.f/512) - mean*mean;
  float inv = rsqrtf(var + 1e-5f);
  u16* xo = xn + (size_t)row * 512;
  xo[t]     = f2b((v0-mean)*inv*w[t]     + b[t]);
  xo[t+256] = f2b((v1-mean)*inv*w[t+256] + b[t+256]);
}

// ---------------- weight transpose + cast: WT[c][r] = W[r][c] ----------------
__global__ __launch_bounds__(256) void wcast_T(const float* __restrict__ W, u16* __restrict__ WT, int R, int C) {
  int idx = blockIdx.x*256 + threadIdx.x;
  if (idx >= R*C) return;
  int r = idx / C, c = idx - r*C;
  WT[(size_t)c*R + r] = f2b(W[idx]);
}

// ---------------- 128x128 MFMA GEMM core (A row-major [M,K], BT row-major [N,K]) ----------------
__device__ __forceinline__ void gemm128_core(const u16* __restrict__ A, const u16* __restrict__ BT,
    int K, int ldA, int ldBT, int row0, int col0, u16* As, u16* Bs, f32x4 acc[4][4]) {
  int t = threadIdx.x, lane = t & 63, wid = t >> 6;
  int wr = (wid >> 1) * 64, wc = (wid & 1) * 64;
  int lr = lane & 15, lg = lane >> 4;
  for (int k0 = 0; k0 < K; k0 += 32) {
    __syncthreads();
    #pragma unroll
    for (int p = 0; p < 2; p++) {
      int ch = t + p*256;
      int r = ch >> 2, c = (ch & 3) * 8;
      *(uint4*)&As[r*40 + c] = *(const uint4*)&A[(size_t)(row0 + r)*ldA + k0 + c];
      *(uint4*)&Bs[r*40 + c] = *(const uint4*)&BT[(size_t)(col0 + r)*ldBT + k0 + c];
    }
    __syncthreads();
    s16x8 af[4], bf[4];
    #pragma unroll
    for (int f = 0; f < 4; f++) {
      af[f] = *(s16x8*)&As[(wr + f*16 + lr)*40 + lg*8];
      bf[f] = *(s16x8*)&Bs[(wc + f*16 + lr)*40 + lg*8];
    }
    #pragma unroll
    for (int i = 0; i < 4; i++)
      #pragma unroll
      for (int j = 0; j < 4; j++)
        acc[i][j] = MFMA16(af[i], bf[j], acc[i][j]);
  }
}

// ---------------- QKV: xn[16384,512] @ w_qkvT -> q*0.125, k, v (+vT) bf16 ----------------
__global__ __launch_bounds__(256) void qkv_mfma(const u16* __restrict__ xn, const u16* __restrict__ wT,
    u16* __restrict__ q, u16* __restrict__ k, u16* __restrict__ v, u16* __restrict__ vT) {
  __shared__ u16 As[128*40], Bs[128*40];
  f32x4 acc[4][4];
  #pragma unroll
  for (int i = 0; i < 4; i++)
    #pragma unroll
    for (int j = 0; j < 4; j++) acc[i][j] = (f32x4)0.f;
  int row0 = blockIdx.y*128, col0 = blockIdx.x*128;
  gemm128_core(xn, wT, 512, 512, 512, row0, col0, As, Bs, acc);
  int t = threadIdx.x, lane = t & 63, wid = t >> 6, lr = lane & 15, lg = lane >> 4;
  int wr = (wid >> 1)*64, wc = (wid & 1)*64;
  #pragma unroll
  for (int i = 0; i < 4; i++)
    #pragma unroll
    for (int j = 0; j < 4; j++)
      #pragma unroll
      for (int r = 0; r < 4; r++) {
        int row = row0 + wr + i*16 + lg*4 + r;
        int col = col0 + wc + j*16 + lr;
        float val = acc[i][j][r];
        int part = col >> 9, rem = col & 511, h = rem >> 6, d = rem & 63;
        int b = row >> 12, n = row & 4095;
        size_t bh = (size_t)(b*8 + h);
        size_t dst = (bh*4096 + n)*64 + d;
        if (part == 0)      q[dst] = f2b(val * 0.125f);
        else if (part == 1) k[dst] = f2b(val);
        else { v[dst] = f2b(val); vT[(bh*64 + d)*4096 + n] = f2b(val); }
      }
}

// ---------------- out: outh[16384,512] @ w_outT + b + x -> fp32 ----------------
__global__ __launch_bounds__(256) void out_mfma(const u16* __restrict__ outh, const u16* __restrict__ wT,
    const float* __restrict__ bo, const float* __restrict__ x, float* __restrict__ out) {
  __shared__ u16 As[128*40], Bs[128*40];
  f32x4 acc[4][4];
  #pragma unroll
  for (int i = 0; i < 4; i++)
    #pragma unroll
    for (int j = 0; j < 4; j++) acc[i][j] = (f32x4)0.f;
  int row0 = blockIdx.y*128, col0 = blockIdx.x*128;
  gemm128_core(outh, wT, 512, 512, 512, row0, col0, As, Bs, acc);
  int t = threadIdx.x, lane = t & 63, wid = t >> 6, lr = lane & 15, lg = lane >> 4;
  int wr = (wid >> 1)*64, wc = (wid & 1)*64;
  #pragma unroll
  for (int i = 0; i < 4; i++)
    #pragma unroll
    for (int j = 0; j < 4; j++)
      #pragma unroll
      for (int r = 0; r < 4; r++) {
        int row = row0 + wr + i*16 + lg*4 + r;
        int col = col0 + wc + j*16 + lr;
        size_t idx = (size_t)row*512 + col;
        out[idx] = x[idx] + acc[i][j][r] + bo[col];
      }
}

// ---------------- batched 64x64-tile MFMA GEMM with flexible epilogue ----------------
// C = alpha*(A@B) + diag*I ; B given as BT [N,K]; writes Cn (normal), CT (transposed), CE (7I - C, transposed)
__global__ __launch_bounds__(256) void bmm64(const u16* __restrict__ A, const u16* __restrict__ BT,
    u16* __restrict__ Cn, u16* __restrict__ CT, u16* __restrict__ CE,
    int M, int N, int K, float alpha, float diag) {
  __shared__ u16 As[64*40], Bs[64*40];
  int batch = blockIdx.z;
  const u16* Ab = A  + (size_t)batch*M*K;
  const u16* Bb = BT + (size_t)batch*N*K;
  int row0 = blockIdx.y*64, col0 = blockIdx.x*64;
  int t = threadIdx.x, lane = t & 63, wid = t >> 6, lr = lane & 15, lg = lane >> 4;
  int wr = (wid >> 1)*32, wc = (wid & 1)*32;
  f32x4 acc[2][2];
  #pragma unroll
  for (int i = 0; i < 2; i++)
    #pragma unroll
    for (int j = 0; j < 2; j++) acc[i][j] = (f32x4)0.f;
  for (int k0 = 0; k0 < K; k0 += 32) {
    __syncthreads();
    int r = t >> 2, c = (t & 3)*8;
    *(uint4*)&As[r*40 + c] = *(const uint4*)&Ab[(size_t)(row0 + r)*K + k0 + c];
    *(uint4*)&Bs[r*40 + c] = *(const uint4*)&Bb[(size_t)(col0 + r)*K + k0 + c];
    __syncthreads();
    s16x8 af[2], bf[2];
    #pragma unroll
    for (int f = 0; f < 2; f++) {
      af[f] = *(s16x8*)&As[(wr + f*16 + lr)*40 + lg*8];
      bf[f] = *(s16x8*)&Bs[(wc + f*16 + lr)*40 + lg*8];
    }
    #pragma unroll
    for (int i = 0; i < 2; i++)
      #pragma unroll
      for (int j = 0; j < 2; j++)
        acc[i][j] = MFMA16(af[i], bf[j], acc[i][j]);
  }
  size_t cb = (size_t)batch*M*N;
  #pragma unroll
  for (int i = 0; i < 2; i++)
    #pragma unroll
    for (int j = 0; j < 2; j++)
      #pragma unroll
      for (int r = 0; r < 4; r++) {
        int row = row0 + wr + i*16 + lg*4 + r;
        int col = col0 + wc + j*16 + lr;
        float val = alpha*acc[i][j][r] + (row == col ? diag : 0.f);
        if (Cn) Cn[cb + (size_t)row*N + col] = f2b(val);
        if (CT) CT[cb + (size_t)col*M + row] = f2b(val);
        if (CE) CE[cb + (size_t)col*M + row] = f2b((row == col ? 7.f : 0.f) - val);
      }
}

// ---------------- landmarks (bf16) ----------------
__global__ void landmark_kernel(const u16* __restrict__ q, const u16* __restrict__ k,
                                u16* __restrict__ ql, u16* __restrict__ kl) {
  int idx = blockIdx.x;              // bh*256 + m
  int d = threadIdx.x;               // 64
  size_t base = ((size_t)idx * 16) * 64 + d;
  float sq = 0.f, sk = 0.f;
  #pragma unroll
  for (int j = 0; j < 16; j++) { sq += b2f(q[base + (size_t)j*64]); sk += b2f(k[base + (size_t)j*64]); }
  ql[(size_t)idx*64 + d] = f2b(sq * (1.f/16.f));
  kl[(size_t)idx*64 + d] = f2b(sk * (1.f/16.f));
}

// ---------------- sim2 softmax (fp32 math, bf16 inputs) ----------------
__global__ __launch_bounds__(256) void sim2_softmax(const u16* __restrict__ ql, const u16* __restrict__ kl,
                             float* __restrict__ a2, u16* __restrict__ a2h) {
  int bh = blockIdx.x >> 8;
  int row = blockIdx.x & 255;
  int t = threadIdx.x;
  __shared__ float qr[64];
  __shared__ float red[256];
  if (t < 64) qr[t] = b2f(ql[((size_t)bh*256 + row)*64 + t]);
  __syncthreads();
  const u16* kr = kl + ((size_t)bh*256 + t)*64;
  float s = 0.f;
  for (int d = 0; d < 64; d++) s += qr[d]*b2f(kr[d]);
  red[t] = s; __syncthreads();
  for (int o = 128; o > 0; o >>= 1) { if (t < o) red[t] = fmaxf(red[t], red[t+o]); __syncthreads(); }
  float mx = red[0]; __syncthreads();
  float p = expf(s - mx);
  red[t] = p; __syncthreads();
  for (int o = 128; o > 0; o >>= 1) { if (t < o) red[t] += red[t+o]; __syncthreads(); }
  float inv = 1.f / red[0];
  size_t idx = ((size_t)bh*256 + row)*256 + t;
  a2[idx] = p * inv;
  a2h[idx] = f2b(p * inv);
}

// ---------------- global max of row/col sums of a2 ----------------
__global__ void absmax_kernel(const float* __restrict__ a2, unsigned* __restrict__ scal) {
  int bh = blockIdx.x; int t = threadIdx.x;
  float rs = 0.f, cs = 0.f;
  const float* rp = a2 + ((size_t)bh*256 + t)*256;
  for (int j = 0; j < 256; j++) rs += rp[j];
  const float* cp = a2 + (size_t)bh*65536 + t;
  for (int i = 0; i < 256; i++) cs += cp[(size_t)i*256];
  __shared__ float r1[256], r2[256];
  r1[t] = rs; r2[t] = cs; __syncthreads();
  for (int o = 128; o > 0; o >>= 1) {
    if (t < o) { r1[t]=fmaxf(r1[t],r1[t+o]); r2[t]=fmaxf(r2[t],r2[t+o]); }
    __syncthreads();
  }
  if (t == 0) {
    atomicMax(scal + 0, __float_as_uint(r1[0]));
    atomicMax(scal + 1, __float_as_uint(r2[0]));
  }
}

// ---------------- z0 = a2^T / (cmax*rmax) -> bf16 normal + transposed ----------------
__global__ void z0_kernel(const float* __restrict__ a2, const unsigned* __restrict__ scal,
                          u16* __restrict__ zA, u16* __restrict__ zAT) {
  size_t idx = (size_t)blockIdx.x*256 + threadIdx.x;
  float inv = 1.f / (__uint_as_float(scal[0]) * __uint_as_float(scal[1]));
  size_t bh = idx >> 16; int rem = (int)(idx & 65535); int i = rem >> 8, j = rem & 255;
  zA[idx]  = f2b(a2[(bh<<16) + ((size_t)j<<8) + i] * inv);
  zAT[idx] = f2b(a2[idx] * inv);
}

// ---------------- MFMA flash: O = softmax(Q K^T) V, D=64; V given transposed VT[bh,64,NK] ----------------
// mode 0: O -> OT[bh,64,NQ] bf16 ; mode 1: O -> outh[(b*4096+n)*512 + h*64 + d] bf16
__global__ __launch_bounds__(256) void flash_mfma(const u16* __restrict__ Q, const u16* __restrict__ Kg,
    const u16* __restrict__ VT, u16* __restrict__ O, int NQ, int NK, int mode) {
  __shared__ u16 Ks[64*72];
  __shared__ u16 Vs[64*72];
  __shared__ u16 Ps[4*16*72];
  int bh = blockIdx.y;
  int q0 = blockIdx.x * 64;
  int t = threadIdx.x, lane = t & 63, wid = t >> 6, lr = lane & 15, lg = lane >> 4;
  const u16* Qb  = Q  + ((size_t)bh*NQ)*64;
  const u16* Kb  = Kg + ((size_t)bh*NK)*64;
  const u16* VTb = VT + ((size_t)bh*64)*NK;
  int qrow = q0 + wid*16 + lr;
  s16x8 aq0 = *(const s16x8*)&Qb[(size_t)qrow*64 + lg*8];
  s16x8 aq1 = *(const s16x8*)&Qb[(size_t)qrow*64 + 32 + lg*8];
  f32x4 oacc[4];
  #pragma unroll
  for (int f = 0; f < 4; f++) oacc[f] = (f32x4)0.f;
  float m_[4] = {-3e38f, -3e38f, -3e38f, -3e38f};
  float l_[4] = {0.f, 0.f, 0.f, 0.f};
  u16* Pw = Ps + wid*16*72;
  for (int k0 = 0; k0 < NK; k0 += 64) {
    __syncthreads();
    #pragma unroll
    for (int p = 0; p < 2; p++) {
      int ch = t + p*256; int r = ch >> 3, c = (ch & 7)*8;
      *(uint4*)&Ks[r*72 + c] = *(const uint4*)&Kb[(size_t)(k0 + r)*64 + c];
      *(uint4*)&Vs[r*72 + c] = *(const uint4*)&VTb[(size_t)r*NK + k0 + c];
    }
    __syncthreads();
    // S = Q @ K^T : 4 col-frags of 16
    f32x4 sf[4];
    #pragma unroll
    for (int f = 0; f < 4; f++) {
      s16x8 b0 = *(s16x8*)&Ks[(f*16 + lr)*72 + lg*8];
      s16x8 b1 = *(s16x8*)&Ks[(f*16 + lr)*72 + 32 + lg*8];
      f32x4 s = (f32x4)0.f;
      s = MFMA16(aq0, b0, s);
      s = MFMA16(aq1, b1, s);
      sf[f] = s;
    }
    // online softmax (rows = lg*4 + r), write P bf16 to LDS
    #pragma unroll
    for (int r = 0; r < 4; r++) {
      float mx = fmaxf(fmaxf(sf[0][r], sf[1][r]), fmaxf(sf[2][r], sf[3][r]));
      #pragma unroll
      for (int o = 1; o < 16; o <<= 1) mx = fmaxf(mx, __shfl_xor(mx, o));
      float mn = fmaxf(m_[r], mx);
      float sum = 0.f;
      #pragma unroll
      for (int f = 0; f < 4; f++) {
        float pv = __expf(sf[f][r] - mn);
        sum += pv;
        Pw[(lg*4 + r)*72 + f*16 + lr] = f2b(pv);
      }
      #pragma unroll
      for (int o = 1; o < 16; o <<= 1) sum += __shfl_xor(sum, o);
      float sc = __expf(m_[r] - mn);
      l_[r] = l_[r]*sc + sum;
      m_[r] = mn;
      #pragma unroll
      for (int f = 0; f < 4; f++) oacc[f][r] *= sc;
    }
    __syncthreads();
    // O += P @ V
    #pragma unroll
    for (int ks = 0; ks < 2; ks++) {
      s16x8 ap = *(s16x8*)&Pw[lr*72 + ks*32 + lg*8];
      #pragma unroll
      for (int df = 0; df < 4; df++) {
        s16x8 bv = *(s16x8*)&Vs[(df*16 + lr)*72 + ks*32 + lg*8];
        oacc[df] = MFMA16(ap, bv, oacc[df]);
      }
    }
  }
  #pragma unroll
  for (int df = 0; df < 4; df++)
    #pragma unroll
    for (int r = 0; r < 4; r++) {
      int lrow = wid*16 + lg*4 + r;
      int col = df*16 + lr;
      float val = oacc[df][r] / l_[r];
      if (mode == 0) O[((size_t)bh*64 + col)*NQ + q0 + lrow] = f2b(val);
      else {
        int b = bh >> 3, h = bh & 7;
        O[((size_t)(b*4096 + q0 + lrow))*512 + h*64 + col] = f2b(val);
      }
    }
}

// ---------------- residual depthwise conv, add into outh (bf16) ----------------
__global__ __launch_bounds__(256) void conv_kernel(const u16* __restrict__ v, const float* __restrict__ rw,
                            u16* __restrict__ outh) {
  size_t i = (size_t)blockIdx.x*256 + threadIdx.x;   // 2,097,152 = 16384*512/4
  int c4 = (int)(i & 127); int h = c4 >> 4; int d0 = (c4 & 15) << 2;
  int n = (int)((i >> 7) & 4095); int b = (int)(i >> 19);
  const u16* vb = v + (((size_t)(b*8 + h))*4096)*64 + d0;
  float s0=0.f, s1=0.f, s2=0.f, s3=0.f;
  #pragma unroll
  for (int j = 0; j < 33; j++) {
    int nn = n + j - 16;
    if (nn < 0 || nn >= 4096) continue;
    uint2 vv = *(const uint2*)(vb + (size_t)nn*64);
    float w = rw[h*33 + j];
    s0 += b2f((u16)(vv.x & 0xffff)) * w;
    s1 += b2f((u16)(vv.x >> 16)) * w;
    s2 += b2f((u16)(vv.y & 0xffff)) * w;
    s3 += b2f((u16)(vv.y >> 16)) * w;
  }
  size_t oi = ((size_t)(b*4096 + n))*512 + h*64 + d0;
  uint2 ov = *(uint2*)(outh + oi);
  unsigned lo = (unsigned)f2b(b2f((u16)(ov.x & 0xffff)) + s0) | ((unsigned)f2b(b2f((u16)(ov.x >> 16)) + s1) << 16);
  unsigned hi = (unsigned)f2b(b2f((u16)(ov.y & 0xffff)) + s2) | ((unsigned)f2b(b2f((u16)(ov.y >> 16)) + s3) << 16);
  uint2 nv; nv.x = lo; nv.y = hi;
  *(uint2*)(outh + oi) = nv;
}

extern "C" void kernel_launch(void* const* d_in, const int* in_sizes, int n_in,
                              void* d_out, int out_size, void* d_ws, size_t ws_size,
                              hipStream_t stream) {
  const float* x      = (const float*)d_in[0];
  const float* norm_w = (const float*)d_in[1];
  const float* norm_b = (const float*)d_in[2];
  const float* w_qkv  = (const float*)d_in[3];
  const float* w_out  = (const float*)d_in[4];
  const float* b_out  = (const float*)d_in[5];
  const float* res_w  = (const float*)d_in[6];
  float* out = (float*)d_out;
  char* ws = (char*)d_ws;

  size_t off = 0;
  u16* xn    = (u16*)(ws + off); off += 16777216;
  u16* q     = (u16*)(ws + off); off += 16777216;
  u16* k     = (u16*)(ws + off); off += 16777216;
  u16* v     = (u16*)(ws + off); off += 16777216;
  u16* vT    = (u16*)(ws + off); off += 16777216;
  u16* ql    = (u16*)(ws + off); off += 1048576;
  u16* kl    = (u16*)(ws + off); off += 1048576;
  float* a2  = (float*)(ws + off); off += 8388608;
  u16* a2h   = (u16*)(ws + off); off += 4194304;
  u16* zA    = (u16*)(ws + off); off += 4194304;
  u16* zAT   = (u16*)(ws + off); off += 4194304;
  u16* zB    = (u16*)(ws + off); off += 4194304;
  u16* zBT   = (u16*)(ws + off); off += 4194304;
  u16* xz    = (u16*)(ws + off); off += 4194304;
  u16* e1T   = (u16*)(ws + off); off += 4194304;
  u16* e2T   = (u16*)(ws + off); off += 4194304;
  u16* e3T   = (u16*)(ws + off); off += 4194304;
  u16* a3vT  = (u16*)(ws + off); off += 1048576;
  u16* w2T   = (u16*)(ws + off); off += 1048576;
  u16* wqkvT = (u16*)(ws + off); off += 1572864;   // 1536x512 bf16
  u16* woutT = (u16*)(ws + off); off += 524288;    // 512x512 bf16
  u16* outh  = (u16*)(ws + off); off += 16777216;
  unsigned* scal = (unsigned*)(ws + off); off += 8;

  ln_kernel<<<16384, 256, 0, stream>>>(x, norm_w, norm_b, xn);
  wcast_T<<<3072, 256, 0, stream>>>(w_qkv, wqkvT, 512, 1536);
  wcast_T<<<1024, 256, 0, stream>>>(w_out, woutT, 512, 512);
  qkv_mfma<<<dim3(12, 128), 256, 0, stream>>>(xn, wqkvT, q, k, v, vT);
  landmark_kernel<<<8192, 64, 0, stream>>>(q, k, ql, kl);
  sim2_softmax<<<8192, 256, 0, stream>>>(ql, kl, a2, a2h);
  hipMemsetAsync(scal, 0, 8, stream);
  absmax_kernel<<<32, 256, 0, stream>>>(a2, scal);
  z0_kernel<<<8192, 256, 0, stream>>>(a2, scal, zA, zAT);

  u16 *zc = zA, *zcT = zAT, *zn = zB, *znT = zBT;
  for (int it = 0; it < 6; it++) {
    // xz = a2 @ z ; e1T = (7I - xz)^T
    bmm64<<<dim3(4,4,32), 256, 0, stream>>>(a2h, zcT, xz, nullptr, e1T, 256,256,256, 1.f, 0.f);
    // e2 = 15I - xz@e1 (transposed out)
    bmm64<<<dim3(4,4,32), 256, 0, stream>>>(xz, e1T, nullptr, e2T, nullptr, 256,256,256, -1.f, 15.f);
    // e3 = 13I - xz@e2 (transposed out)
    bmm64<<<dim3(4,4,32), 256, 0, stream>>>(xz, e2T, nullptr, e3T, nullptr, 256,256,256, -1.f, 13.f);
    // zn = 0.25 * z@e3 (normal + transposed)
    bmm64<<<dim3(4,4,32), 256, 0, stream>>>(zc, e3T, zn, znT, nullptr, 256,256,256, 0.25f, 0.f);
    u16* tp;
    tp = zc; zc = zn; zn = tp;
    tp = zcT; zcT = znT; znT = tp;
  }

  // a3v^T = (softmax(ql @ k^T) @ v)^T  -> [bh,64,256]
  flash_mfma<<<dim3(4, 32), 256, 0, stream>>>(ql, k, vT, a3vT, 256, 4096, 0);
  // w2^T = (a2_inv @ a3v)^T -> [bh,64,256]
  bmm64<<<dim3(1,4,32), 256, 0, stream>>>(zc, a3vT, nullptr, w2T, nullptr, 256, 64, 256, 1.f, 0.f);
  // outh = softmax(q @ kl^T) @ w2 -> [B,N,H*D] bf16
  flash_mfma<<<dim3(64, 32), 256, 0, stream>>>(q, kl, w2T, outh, 4096, 256, 1);
  // outh += depthwise conv of v
  conv_kernel<<<8192, 256, 0, stream>>>(v, res_w, outh);
  // out = x + outh @ w_out + b_out
  out_mfma<<<dim3(4, 128), 256, 0, stream>>>(outh, woutT, b_out, x, out);
}

// Round 3
// 544.173 us; speedup vs baseline: 6.0477x; 1.1565x over previous
//
#include <hip/hip_runtime.h>
#include <math.h>

typedef unsigned short u16;
typedef short s16x8 __attribute__((ext_vector_type(8)));
typedef float f32x4 __attribute__((ext_vector_type(4)));

#define MFMA16(a, b, c) __builtin_amdgcn_mfma_f32_16x16x32_bf16((a), (b), (c), 0, 0, 0)

__device__ __forceinline__ u16 f2b(float f) {
  unsigned u = __float_as_uint(f);
  unsigned r = (u + 0x7fff + ((u >> 16) & 1)) >> 16;
  return (u16)r;
}
__device__ __forceinline__ float b2f(u16 h) { return __uint_as_float(((unsigned)h) << 16); }

// ---------------- LayerNorm -> bf16 ----------------
__global__ __launch_bounds__(256) void ln_kernel(const float* __restrict__ x, const float* __restrict__ w,
                          const float* __restrict__ b, u16* __restrict__ xn) {
  int row = blockIdx.x;
  const float* xr = x + (size_t)row * 512;
  int t = threadIdx.x;
  float v0 = xr[t], v1 = xr[t + 256];
  float s = v0 + v1, ss = v0*v0 + v1*v1;
  for (int o = 32; o > 0; o >>= 1) { s += __shfl_down(s, o); ss += __shfl_down(ss, o); }
  __shared__ float ls[4], lss[4];
  int wid = t >> 6, lane = t & 63;
  if (lane == 0) { ls[wid] = s; lss[wid] = ss; }
  __syncthreads();
  float tot  = ls[0]+ls[1]+ls[2]+ls[3];
  float tot2 = lss[0]+lss[1]+lss[2]+lss[3];
  float mean = tot * (1.f/512);
  float var  = tot2 * (1.f/512) - mean*mean;
  float inv = rsqrtf(var + 1e-5f);
  u16* xo = xn + (size_t)row * 512;
  xo[t]     = f2b((v0-mean)*inv*w[t]     + b[t]);
  xo[t+256] = f2b((v1-mean)*inv*w[t+256] + b[t+256]);
}

// ---------------- weight transpose + cast: WT[c][r] = W[r][c] ----------------
__global__ __launch_bounds__(256) void wcast_T(const float* __restrict__ W, u16* __restrict__ WT, int R, int C) {
  int idx = blockIdx.x*256 + threadIdx.x;
  if (idx >= R*C) return;
  int r = idx / C, c = idx - r*C;
  WT[(size_t)c*R + r] = f2b(W[idx]);
}

// ---------------- v transpose: v[bh,4096,64] -> vT[bh,64,4096] ----------------
__global__ __launch_bounds__(256) void vtrans(const u16* __restrict__ v, u16* __restrict__ vT) {
  __shared__ u16 tile[64][72];
  int bh = blockIdx.y, n0 = blockIdx.x * 64;
  int t = threadIdx.x;
  const u16* vb = v + ((size_t)bh*4096 + n0)*64;
  #pragma unroll
  for (int p = 0; p < 2; p++) {
    int c = t + p*256;
    int r = c >> 3, col = (c & 7)*8;
    *(uint4*)&tile[r][col] = *(const uint4*)&vb[(size_t)r*64 + col];
  }
  __syncthreads();
  #pragma unroll
  for (int p = 0; p < 2; p++) {
    int c = t + p*256;
    int d = c >> 3, ncol = (c & 7)*8;
    u16 tmp[8];
    #pragma unroll
    for (int j = 0; j < 8; j++) tmp[j] = tile[ncol + j][d];
    *(uint4*)&vT[((size_t)bh*64 + d)*4096 + n0 + ncol] = *(uint4*)tmp;
  }
}

// ---------------- 128x128 MFMA GEMM core ----------------
__device__ __forceinline__ void gemm128_core(const u16* __restrict__ A, const u16* __restrict__ BT,
    int K, int ldA, int ldBT, int row0, int col0, u16* As, u16* Bs, f32x4 acc[4][4]) {
  int t = threadIdx.x, lane = t & 63, wid = t >> 6;
  int wr = (wid >> 1) * 64, wc = (wid & 1) * 64;
  int lr = lane & 15, lg = lane >> 4;
  for (int k0 = 0; k0 < K; k0 += 32) {
    __syncthreads();
    #pragma unroll
    for (int p = 0; p < 2; p++) {
      int ch = t + p*256;
      int r = ch >> 2, c = (ch & 3) * 8;
      *(uint4*)&As[r*40 + c] = *(const uint4*)&A[(size_t)(row0 + r)*ldA + k0 + c];
      *(uint4*)&Bs[r*40 + c] = *(const uint4*)&BT[(size_t)(col0 + r)*ldBT + k0 + c];
    }
    __syncthreads();
    s16x8 af[4], bf[4];
    #pragma unroll
    for (int f = 0; f < 4; f++) {
      af[f] = *(s16x8*)&As[(wr + f*16 + lr)*40 + lg*8];
      bf[f] = *(s16x8*)&Bs[(wc + f*16 + lr)*40 + lg*8];
    }
    #pragma unroll
    for (int i = 0; i < 4; i++)
      #pragma unroll
      for (int j = 0; j < 4; j++)
        acc[i][j] = MFMA16(af[i], bf[j], acc[i][j]);
  }
}

// ---------------- QKV: xn[16384,512] @ w_qkvT -> q*0.125, k, v ----------------
__global__ __launch_bounds__(256) void qkv_mfma(const u16* __restrict__ xn, const u16* __restrict__ wT,
    u16* __restrict__ q, u16* __restrict__ k, u16* __restrict__ v) {
  __shared__ u16 As[128*40], Bs[128*40];
  f32x4 acc[4][4];
  #pragma unroll
  for (int i = 0; i < 4; i++)
    #pragma unroll
    for (int j = 0; j < 4; j++) acc[i][j] = (f32x4)0.f;
  int row0 = blockIdx.y*128, col0 = blockIdx.x*128;
  gemm128_core(xn, wT, 512, 512, 512, row0, col0, As, Bs, acc);
  int t = threadIdx.x, lane = t & 63, wid = t >> 6, lr = lane & 15, lg = lane >> 4;
  int wr = (wid >> 1)*64, wc = (wid & 1)*64;
  #pragma unroll
  for (int i = 0; i < 4; i++)
    #pragma unroll
    for (int j = 0; j < 4; j++)
      #pragma unroll
      for (int r = 0; r < 4; r++) {
        int row = row0 + wr + i*16 + lg*4 + r;
        int col = col0 + wc + j*16 + lr;
        float val = acc[i][j][r];
        int part = col >> 9, rem = col & 511, h = rem >> 6, d = rem & 63;
        int b = row >> 12, n = row & 4095;
        size_t bh = (size_t)(b*8 + h);
        size_t dst = (bh*4096 + n)*64 + d;
        if (part == 0)      q[dst] = f2b(val * 0.125f);
        else if (part == 1) k[dst] = f2b(val);
        else                v[dst] = f2b(val);
      }
}

// ---------------- out: outh[16384,512] @ w_outT + b + x -> fp32 ----------------
__global__ __launch_bounds__(256) void out_mfma(const u16* __restrict__ outh, const u16* __restrict__ wT,
    const float* __restrict__ bo, const float* __restrict__ x, float* __restrict__ out) {
  __shared__ u16 As[128*40], Bs[128*40];
  f32x4 acc[4][4];
  #pragma unroll
  for (int i = 0; i < 4; i++)
    #pragma unroll
    for (int j = 0; j < 4; j++) acc[i][j] = (f32x4)0.f;
  int row0 = blockIdx.y*128, col0 = blockIdx.x*128;
  gemm128_core(outh, wT, 512, 512, 512, row0, col0, As, Bs, acc);
  int t = threadIdx.x, lane = t & 63, wid = t >> 6, lr = lane & 15, lg = lane >> 4;
  int wr = (wid >> 1)*64, wc = (wid & 1)*64;
  #pragma unroll
  for (int i = 0; i < 4; i++)
    #pragma unroll
    for (int j = 0; j < 4; j++)
      #pragma unroll
      for (int r = 0; r < 4; r++) {
        int row = row0 + wr + i*16 + lg*4 + r;
        int col = col0 + wc + j*16 + lr;
        size_t idx = (size_t)row*512 + col;
        out[idx] = x[idx] + acc[i][j][r] + bo[col];
      }
}

// ---------------- batched 64x64-tile MFMA GEMM with flexible epilogue ----------------
__global__ __launch_bounds__(256) void bmm64(const u16* __restrict__ A, const u16* __restrict__ BT,
    u16* __restrict__ Cn, u16* __restrict__ CT, u16* __restrict__ CE,
    int M, int N, int K, float alpha, float diag) {
  __shared__ u16 As[64*40], Bs[64*40];
  int batch = blockIdx.z;
  const u16* Ab = A  + (size_t)batch*M*K;
  const u16* Bb = BT + (size_t)batch*N*K;
  int row0 = blockIdx.y*64, col0 = blockIdx.x*64;
  int t = threadIdx.x, lane = t & 63, wid = t >> 6, lr = lane & 15, lg = lane >> 4;
  int wr = (wid >> 1)*32, wc = (wid & 1)*32;
  f32x4 acc[2][2];
  #pragma unroll
  for (int i = 0; i < 2; i++)
    #pragma unroll
    for (int j = 0; j < 2; j++) acc[i][j] = (f32x4)0.f;
  for (int k0 = 0; k0 < K; k0 += 32) {
    __syncthreads();
    int r = t >> 2, c = (t & 3)*8;
    *(uint4*)&As[r*40 + c] = *(const uint4*)&Ab[(size_t)(row0 + r)*K + k0 + c];
    *(uint4*)&Bs[r*40 + c] = *(const uint4*)&Bb[(size_t)(col0 + r)*K + k0 + c];
    __syncthreads();
    s16x8 af[2], bf[2];
    #pragma unroll
    for (int f = 0; f < 2; f++) {
      af[f] = *(s16x8*)&As[(wr + f*16 + lr)*40 + lg*8];
      bf[f] = *(s16x8*)&Bs[(wc + f*16 + lr)*40 + lg*8];
    }
    #pragma unroll
    for (int i = 0; i < 2; i++)
      #pragma unroll
      for (int j = 0; j < 2; j++)
        acc[i][j] = MFMA16(af[i], bf[j], acc[i][j]);
  }
  size_t cb = (size_t)batch*M*N;
  #pragma unroll
  for (int i = 0; i < 2; i++)
    #pragma unroll
    for (int j = 0; j < 2; j++)
      #pragma unroll
      for (int r = 0; r < 4; r++) {
        int row = row0 + wr + i*16 + lg*4 + r;
        int col = col0 + wc + j*16 + lr;
        float val = alpha*acc[i][j][r] + (row == col ? diag : 0.f);
        if (Cn) Cn[cb + (size_t)row*N + col] = f2b(val);
        if (CT) CT[cb + (size_t)col*M + row] = f2b(val);
        if (CE) CE[cb + (size_t)col*M + row] = f2b((row == col ? 7.f : 0.f) - val);
      }
}

// ---------------- landmarks (bf16) ----------------
__global__ void landmark_kernel(const u16* __restrict__ q, const u16* __restrict__ k,
                                u16* __restrict__ ql, u16* __restrict__ kl) {
  int idx = blockIdx.x;
  int d = threadIdx.x;
  size_t base = ((size_t)idx * 16) * 64 + d;
  float sq = 0.f, sk = 0.f;
  #pragma unroll
  for (int j = 0; j < 16; j++) { sq += b2f(q[base + (size_t)j*64]); sk += b2f(k[base + (size_t)j*64]); }
  ql[(size_t)idx*64 + d] = f2b(sq * (1.f/16.f));
  kl[(size_t)idx*64 + d] = f2b(sk * (1.f/16.f));
}

// ---------------- sim2 softmax ----------------
__global__ __launch_bounds__(256) void sim2_softmax(const u16* __restrict__ ql, const u16* __restrict__ kl,
                             float* __restrict__ a2, u16* __restrict__ a2h) {
  int bh = blockIdx.x >> 8;
  int row = blockIdx.x & 255;
  int t = threadIdx.x;
  __shared__ float qr[64];
  __shared__ float red[256];
  if (t < 64) qr[t] = b2f(ql[((size_t)bh*256 + row)*64 + t]);
  __syncthreads();
  const u16* kr = kl + ((size_t)bh*256 + t)*64;
  float s = 0.f;
  for (int d = 0; d < 64; d++) s += qr[d]*b2f(kr[d]);
  red[t] = s; __syncthreads();
  for (int o = 128; o > 0; o >>= 1) { if (t < o) red[t] = fmaxf(red[t], red[t+o]); __syncthreads(); }
  float mx = red[0]; __syncthreads();
  float p = expf(s - mx);
  red[t] = p; __syncthreads();
  for (int o = 128; o > 0; o >>= 1) { if (t < o) red[t] += red[t+o]; __syncthreads(); }
  float inv = 1.f / red[0];
  size_t idx = ((size_t)bh*256 + row)*256 + t;
  a2[idx] = p * inv;
  a2h[idx] = f2b(p * inv);
}

// ---------------- global max of row/col sums of a2 ----------------
__global__ void absmax_kernel(const float* __restrict__ a2, unsigned* __restrict__ scal) {
  int bh = blockIdx.x; int t = threadIdx.x;
  float rs = 0.f, cs = 0.f;
  const float* rp = a2 + ((size_t)bh*256 + t)*256;
  for (int j = 0; j < 256; j++) rs += rp[j];
  const float* cp = a2 + (size_t)bh*65536 + t;
  for (int i = 0; i < 256; i++) cs += cp[(size_t)i*256];
  __shared__ float r1[256], r2[256];
  r1[t] = rs; r2[t] = cs; __syncthreads();
  for (int o = 128; o > 0; o >>= 1) {
    if (t < o) { r1[t]=fmaxf(r1[t],r1[t+o]); r2[t]=fmaxf(r2[t],r2[t+o]); }
    __syncthreads();
  }
  if (t == 0) {
    atomicMax(scal + 0, __float_as_uint(r1[0]));
    atomicMax(scal + 1, __float_as_uint(r2[0]));
  }
}

// ---------------- z0 = a2^T / (cmax*rmax) ----------------
__global__ void z0_kernel(const float* __restrict__ a2, const unsigned* __restrict__ scal,
                          u16* __restrict__ zA, u16* __restrict__ zAT) {
  size_t idx = (size_t)blockIdx.x*256 + threadIdx.x;
  float inv = 1.f / (__uint_as_float(scal[0]) * __uint_as_float(scal[1]));
  size_t bh = idx >> 16; int rem = (int)(idx & 65535); int i = rem >> 8, j = rem & 255;
  zA[idx]  = f2b(a2[(bh<<16) + ((size_t)j<<8) + i] * inv);
  zAT[idx] = f2b(a2[idx] * inv);
}

// ---------------- split-K flash partials: softmax(ql @ k^T) @ v over a 512-key chunk ----------------
// grid (4 qt, 8 ch, 32 bh); writes unnormalized (m, l, O) per (chunk, row)
__global__ __launch_bounds__(256) void flash_part(const u16* __restrict__ Q, const u16* __restrict__ Kg,
    const u16* __restrict__ VT, float* __restrict__ po, float* __restrict__ pm, float* __restrict__ pl) {
  __shared__ u16 Ks[64*72];
  __shared__ u16 Vs[64*72];
  __shared__ u16 Ps[4*16*72];
  int qt = blockIdx.x, ch = blockIdx.y, bh = blockIdx.z;
  int q0 = qt * 64;
  int t = threadIdx.x, lane = t & 63, wid = t >> 6, lr = lane & 15, lg = lane >> 4;
  const u16* Qb  = Q  + ((size_t)bh*256)*64;
  const u16* Kb  = Kg + ((size_t)bh*4096 + ch*512)*64;
  const u16* VTb = VT + ((size_t)bh*64)*4096 + ch*512;
  int qrow = q0 + wid*16 + lr;
  s16x8 aq0 = *(const s16x8*)&Qb[(size_t)qrow*64 + lg*8];
  s16x8 aq1 = *(const s16x8*)&Qb[(size_t)qrow*64 + 32 + lg*8];
  f32x4 oacc[4];
  #pragma unroll
  for (int f = 0; f < 4; f++) oacc[f] = (f32x4)0.f;
  float m_[4] = {-3e38f, -3e38f, -3e38f, -3e38f};
  float l_[4] = {0.f, 0.f, 0.f, 0.f};
  u16* Pw = Ps + wid*16*72;
  for (int k0 = 0; k0 < 512; k0 += 64) {
    __syncthreads();
    #pragma unroll
    for (int p = 0; p < 2; p++) {
      int c = t + p*256; int r = c >> 3, cc = (c & 7)*8;
      *(uint4*)&Ks[r*72 + cc] = *(const uint4*)&Kb[(size_t)(k0 + r)*64 + cc];
      *(uint4*)&Vs[r*72 + cc] = *(const uint4*)&VTb[(size_t)r*4096 + k0 + cc];
    }
    __syncthreads();
    f32x4 sf[4];
    #pragma unroll
    for (int f = 0; f < 4; f++) {
      s16x8 b0 = *(s16x8*)&Ks[(f*16 + lr)*72 + lg*8];
      s16x8 b1 = *(s16x8*)&Ks[(f*16 + lr)*72 + 32 + lg*8];
      f32x4 s = (f32x4)0.f;
      s = MFMA16(aq0, b0, s);
      s = MFMA16(aq1, b1, s);
      sf[f] = s;
    }
    #pragma unroll
    for (int r = 0; r < 4; r++) {
      float mx = fmaxf(fmaxf(sf[0][r], sf[1][r]), fmaxf(sf[2][r], sf[3][r]));
      #pragma unroll
      for (int o = 1; o < 16; o <<= 1) mx = fmaxf(mx, __shfl_xor(mx, o));
      float mn = fmaxf(m_[r], mx);
      float sum = 0.f;
      #pragma unroll
      for (int f = 0; f < 4; f++) {
        float pv = __expf(sf[f][r] - mn);
        sum += pv;
        Pw[(lg*4 + r)*72 + f*16 + lr] = f2b(pv);
      }
      #pragma unroll
      for (int o = 1; o < 16; o <<= 1) sum += __shfl_xor(sum, o);
      float sc = __expf(m_[r] - mn);
      l_[r] = l_[r]*sc + sum;
      m_[r] = mn;
      #pragma unroll
      for (int f = 0; f < 4; f++) oacc[f][r] *= sc;
    }
    __syncthreads();
    #pragma unroll
    for (int ks = 0; ks < 2; ks++) {
      s16x8 ap = *(s16x8*)&Pw[lr*72 + ks*32 + lg*8];
      #pragma unroll
      for (int df = 0; df < 4; df++) {
        s16x8 bv = *(s16x8*)&Vs[(df*16 + lr)*72 + ks*32 + lg*8];
        oacc[df] = MFMA16(ap, bv, oacc[df]);
      }
    }
  }
  int pidx = (bh*4 + qt)*8 + ch;
  #pragma unroll
  for (int r = 0; r < 4; r++) {
    int lrow = wid*16 + lg*4 + r;
    if (lr == 0) { pm[pidx*64 + lrow] = m_[r]; pl[pidx*64 + lrow] = l_[r]; }
    #pragma unroll
    for (int df = 0; df < 4; df++)
      po[((size_t)pidx*64 + lrow)*64 + df*16 + lr] = oacc[df][r];
  }
}

// ---------------- merge 8 chunk-partials -> a3vT[bh,64,256] ----------------
__global__ __launch_bounds__(256) void flash_merge(const float* __restrict__ po, const float* __restrict__ pm,
    const float* __restrict__ pl, u16* __restrict__ a3vT) {
  int row = blockIdx.x*4 + (threadIdx.x >> 6);   // 8192 rows
  int d = threadIdx.x & 63;
  int bh = row >> 8, qrow = row & 255, qt = qrow >> 6, lrow = qrow & 63;
  int pbase = (bh*4 + qt)*8;
  float m = -3e38f;
  #pragma unroll
  for (int ch = 0; ch < 8; ch++) m = fmaxf(m, pm[(pbase+ch)*64 + lrow]);
  float L = 0.f, O = 0.f;
  #pragma unroll
  for (int ch = 0; ch < 8; ch++) {
    float w = __expf(pm[(pbase+ch)*64 + lrow] - m);
    L += w * pl[(pbase+ch)*64 + lrow];
    O += w * po[((size_t)(pbase+ch)*64 + lrow)*64 + d];
  }
  a3vT[((size_t)bh*64 + d)*256 + qrow] = f2b(O / L);
}

// ---------------- exact-softmax flash: outh = softmax(q @ kl^T) @ w2, NK=256 ----------------
__global__ __launch_bounds__(256) void flash_a1(const u16* __restrict__ Q, const u16* __restrict__ Kl,
    const u16* __restrict__ W2T, u16* __restrict__ outh) {
  __shared__ u16 Ks[64*72];
  __shared__ u16 Vs[64*264];
  __shared__ u16 Ps[4*16*264];
  int bh = blockIdx.y;
  int q0 = blockIdx.x * 64;
  int t = threadIdx.x, lane = t & 63, wid = t >> 6, lr = lane & 15, lg = lane >> 4;
  const u16* Qb = Q + ((size_t)bh*4096)*64;
  // stage V (w2T) once: 64 x 256
  #pragma unroll
  for (int p = 0; p < 8; p++) {
    int c = t + p*256; int r = c >> 5, col = (c & 31)*8;
    *(uint4*)&Vs[r*264 + col] = *(const uint4*)&W2T[((size_t)bh*64 + r)*256 + col];
  }
  int qrow = q0 + wid*16 + lr;
  s16x8 aq0 = *(const s16x8*)&Qb[(size_t)qrow*64 + lg*8];
  s16x8 aq1 = *(const s16x8*)&Qb[(size_t)qrow*64 + 32 + lg*8];
  f32x4 sf[16];
  #pragma unroll
  for (int f = 0; f < 16; f++) sf[f] = (f32x4)0.f;
  #pragma unroll
  for (int kt = 0; kt < 4; kt++) {
    __syncthreads();
    #pragma unroll
    for (int p = 0; p < 2; p++) {
      int c = t + p*256; int r = c >> 3, cc = (c & 7)*8;
      *(uint4*)&Ks[r*72 + cc] = *(const uint4*)&Kl[((size_t)bh*256 + kt*64 + r)*64 + cc];
    }
    __syncthreads();
    #pragma unroll
    for (int f2 = 0; f2 < 4; f2++) {
      s16x8 b0 = *(s16x8*)&Ks[(f2*16 + lr)*72 + lg*8];
      s16x8 b1 = *(s16x8*)&Ks[(f2*16 + lr)*72 + 32 + lg*8];
      sf[kt*4 + f2] = MFMA16(aq1, b1, MFMA16(aq0, b0, sf[kt*4 + f2]));
    }
  }
  // exact softmax over 256 cols held in sf[16]
  u16* Pw = Ps + wid*16*264;
  float linv[4];
  #pragma unroll
  for (int r = 0; r < 4; r++) {
    float mx = -3e38f;
    #pragma unroll
    for (int f = 0; f < 16; f++) mx = fmaxf(mx, sf[f][r]);
    #pragma unroll
    for (int o = 1; o < 16; o <<= 1) mx = fmaxf(mx, __shfl_xor(mx, o));
    float sum = 0.f;
    #pragma unroll
    for (int f = 0; f < 16; f++) {
      float pv = __expf(sf[f][r] - mx);
      sum += pv;
      Pw[(lg*4 + r)*264 + f*16 + lr] = f2b(pv);
    }
    #pragma unroll
    for (int o = 1; o < 16; o <<= 1) sum += __shfl_xor(sum, o);
    linv[r] = 1.f / sum;
  }
  // PV: P[16x256] @ V[256x64]  (own-warp P, Vs synced by kt-loop barriers)
  f32x4 oacc[4];
  #pragma unroll
  for (int f = 0; f < 4; f++) oacc[f] = (f32x4)0.f;
  #pragma unroll
  for (int ks = 0; ks < 8; ks++) {
    s16x8 ap = *(s16x8*)&Pw[lr*264 + ks*32 + lg*8];
    #pragma unroll
    for (int df = 0; df < 4; df++) {
      s16x8 bv = *(s16x8*)&Vs[(df*16 + lr)*264 + ks*32 + lg*8];
      oacc[df] = MFMA16(ap, bv, oacc[df]);
    }
  }
  int b = bh >> 3, h = bh & 7;
  #pragma unroll
  for (int df = 0; df < 4; df++)
    #pragma unroll
    for (int r = 0; r < 4; r++) {
      int lrow = wid*16 + lg*4 + r;
      int col = df*16 + lr;
      outh[((size_t)(b*4096 + q0 + lrow))*512 + h*64 + col] = f2b(oacc[df][r] * linv[r]);
    }
}

// ---------------- residual depthwise conv, add into outh (bf16) ----------------
__global__ __launch_bounds__(256) void conv_kernel(const u16* __restrict__ v, const float* __restrict__ rw,
                            u16* __restrict__ outh) {
  size_t i = (size_t)blockIdx.x*256 + threadIdx.x;
  int c4 = (int)(i & 127); int h = c4 >> 4; int d0 = (c4 & 15) << 2;
  int n = (int)((i >> 7) & 4095); int b = (int)(i >> 19);
  const u16* vb = v + (((size_t)(b*8 + h))*4096)*64 + d0;
  float s0=0.f, s1=0.f, s2=0.f, s3=0.f;
  #pragma unroll
  for (int j = 0; j < 33; j++) {
    int nn = n + j - 16;
    if (nn < 0 || nn >= 4096) continue;
    uint2 vv = *(const uint2*)(vb + (size_t)nn*64);
    float w = rw[h*33 + j];
    s0 += b2f((u16)(vv.x & 0xffff)) * w;
    s1 += b2f((u16)(vv.x >> 16)) * w;
    s2 += b2f((u16)(vv.y & 0xffff)) * w;
    s3 += b2f((u16)(vv.y >> 16)) * w;
  }
  size_t oi = ((size_t)(b*4096 + n))*512 + h*64 + d0;
  uint2 ov = *(uint2*)(outh + oi);
  unsigned lo = (unsigned)f2b(b2f((u16)(ov.x & 0xffff)) + s0) | ((unsigned)f2b(b2f((u16)(ov.x >> 16)) + s1) << 16);
  unsigned hi = (unsigned)f2b(b2f((u16)(ov.y & 0xffff)) + s2) | ((unsigned)f2b(b2f((u16)(ov.y >> 16)) + s3) << 16);
  uint2 nv; nv.x = lo; nv.y = hi;
  *(uint2*)(outh + oi) = nv;
}

extern "C" void kernel_launch(void* const* d_in, const int* in_sizes, int n_in,
                              void* d_out, int out_size, void* d_ws, size_t ws_size,
                              hipStream_t stream) {
  const float* x      = (const float*)d_in[0];
  const float* norm_w = (const float*)d_in[1];
  const float* norm_b = (const float*)d_in[2];
  const float* w_qkv  = (const float*)d_in[3];
  const float* w_out  = (const float*)d_in[4];
  const float* b_out  = (const float*)d_in[5];
  const float* res_w  = (const float*)d_in[6];
  float* out = (float*)d_out;
  char* ws = (char*)d_ws;

  size_t off = 0;
  u16* xn    = (u16*)(ws + off); off += 16777216;
  u16* q     = (u16*)(ws + off); off += 16777216;
  u16* k     = (u16*)(ws + off); off += 16777216;
  u16* v     = (u16*)(ws + off); off += 16777216;
  u16* vT    = (u16*)(ws + off); off += 16777216;
  u16* ql    = (u16*)(ws + off); off += 1048576;
  u16* kl    = (u16*)(ws + off); off += 1048576;
  float* a2  = (float*)(ws + off); off += 8388608;
  u16* a2h   = (u16*)(ws + off); off += 4194304;
  u16* zA    = (u16*)(ws + off); off += 4194304;
  u16* zAT   = (u16*)(ws + off); off += 4194304;
  u16* zB    = (u16*)(ws + off); off += 4194304;
  u16* zBT   = (u16*)(ws + off); off += 4194304;
  u16* xz    = (u16*)(ws + off); off += 4194304;
  u16* e1T   = (u16*)(ws + off); off += 4194304;
  u16* e2T   = (u16*)(ws + off); off += 4194304;
  u16* e3T   = (u16*)(ws + off); off += 4194304;
  u16* a3vT  = (u16*)(ws + off); off += 1048576;
  u16* w2T   = (u16*)(ws + off); off += 1048576;
  u16* wqkvT = (u16*)(ws + off); off += 1572864;
  u16* woutT = (u16*)(ws + off); off += 524288;
  u16* outh  = (u16*)(ws + off); off += 16777216;
  float* po  = (float*)(ws + off); off += 16777216;   // 1024*64*64 f32
  float* pm  = (float*)(ws + off); off += 262144;
  float* pl  = (float*)(ws + off); off += 262144;
  unsigned* scal = (unsigned*)(ws + off); off += 8;

  ln_kernel<<<16384, 256, 0, stream>>>(x, norm_w, norm_b, xn);
  wcast_T<<<3072, 256, 0, stream>>>(w_qkv, wqkvT, 512, 1536);
  wcast_T<<<1024, 256, 0, stream>>>(w_out, woutT, 512, 512);
  qkv_mfma<<<dim3(12, 128), 256, 0, stream>>>(xn, wqkvT, q, k, v);
  vtrans<<<dim3(64, 32), 256, 0, stream>>>(v, vT);
  landmark_kernel<<<8192, 64, 0, stream>>>(q, k, ql, kl);
  sim2_softmax<<<8192, 256, 0, stream>>>(ql, kl, a2, a2h);
  hipMemsetAsync(scal, 0, 8, stream);
  absmax_kernel<<<32, 256, 0, stream>>>(a2, scal);
  z0_kernel<<<8192, 256, 0, stream>>>(a2, scal, zA, zAT);

  u16 *zc = zA, *zcT = zAT, *zn = zB, *znT = zBT;
  for (int it = 0; it < 6; it++) {
    bmm64<<<dim3(4,4,32), 256, 0, stream>>>(a2h, zcT, xz, nullptr, e1T, 256,256,256, 1.f, 0.f);
    bmm64<<<dim3(4,4,32), 256, 0, stream>>>(xz, e1T, nullptr, e2T, nullptr, 256,256,256, -1.f, 15.f);
    bmm64<<<dim3(4,4,32), 256, 0, stream>>>(xz, e2T, nullptr, e3T, nullptr, 256,256,256, -1.f, 13.f);
    bmm64<<<dim3(4,4,32), 256, 0, stream>>>(zc, e3T, zn, znT, nullptr, 256,256,256, 0.25f, 0.f);
    u16* tp;
    tp = zc; zc = zn; zn = tp;
    tp = zcT; zcT = znT; znT = tp;
  }

  // a3v partials + merge -> a3vT[bh,64,256]
  flash_part<<<dim3(4, 8, 32), 256, 0, stream>>>(ql, k, vT, po, pm, pl);
  flash_merge<<<2048, 256, 0, stream>>>(po, pm, pl, a3vT);
  // w2^T = (a2_inv @ a3v)^T -> [bh,64,256]
  bmm64<<<dim3(1,4,32), 256, 0, stream>>>(zc, a3vT, nullptr, w2T, nullptr, 256, 64, 256, 1.f, 0.f);
  // outh = softmax(q @ kl^T) @ w2 -> [B,N,H*D] bf16
  flash_a1<<<dim3(64, 32), 256, 0, stream>>>(q, kl, w2T, outh);
  // outh += depthwise conv of v
  conv_kernel<<<8192, 256, 0, stream>>>(v, res_w, outh);
  // out = x + outh @ w_out + b_out
  out_mfma<<<dim3(4, 128), 256, 0, stream>>>(outh, woutT, b_out, x, out);
}